// Round 16
// baseline (54.020 us; speedup 1.0000x reference)
//
#include <hip/hip_runtime.h>
#include <math.h>

#define TLEN (1 << 20)
#define SB 32              // reset-chain sub-chunk
#define NSB (TLEN / SB)    // 32768 sub-chunks
#define SCB 512            // maps per scan block
#define NSCB (NSB / SCB)   // 64 scan blocks
#define THRESH 1e-4f
#define IDMAP 0x00FAC688u  // packed identity map: entry g -> g (3 bits each)

#define WWORDS (SCB * SB + 8)      // 16392 staged Z words (8 lead slots)
#define WPAD(i) ((i) + ((i) >> 5)) // +1 word per 32: kills stride-32 bank conflicts
#define LDSW WPAD(WWORDS)

#pragma clang fp contract(off)

// consts layout: 0:w1 1:w2 2:w3 3:w4 4:dt1 5:dt2 6:d2t1 7:d2t2 8:2*w4

// The canonical 32-output chunk program (round-12 PROVEN, verbatim).
#define CHUNK55(OFS, OUTARR) {                                                 \
        const float4* xp_ = (const float4*)(X + (OFS) - 24);                   \
        float xa_[56];                                                         \
        _Pragma("unroll")                                                      \
        for (int q_ = 0; q_ < 14; ++q_) {                                      \
            float4 v_ = xp_[q_];                                               \
            xa_[4 * q_ + 0] = v_.x; xa_[4 * q_ + 1] = v_.y;                    \
            xa_[4 * q_ + 2] = v_.z; xa_[4 * q_ + 3] = v_.w;                    \
        }                                                                      \
        float h_ = 0.0f;                                                       \
        _Pragma("unroll")                                                      \
        for (int p_ = 0; p_ < 55; ++p_) {                                      \
            float x_ = xa_[p_];                                                \
            float t1_ = w1 * x_;                                               \
            float t2_ = w2 * h_;                                               \
            float s1_ = t1_ + t2_;                                             \
            float t3_ = (w3 * x_) * x_;                                        \
            float s2_ = s1_ + t3_;                                             \
            float t4_ = (w4 * h_) * h_;                                        \
            h_ = s2_ + t4_;                                                    \
            if (p_ >= 23) OUTARR[p_ - 23] = h_;                                \
        }                                                                      \
    }

// K1: Z + tables + scan in one launch (round-12 PROVEN, verbatim).
__global__ void __launch_bounds__(512) k_zts(const float* __restrict__ P,
                                             const float* __restrict__ X,
                                             float* __restrict__ c,
                                             float* __restrict__ Z,
                                             unsigned int* __restrict__ L32,
                                             unsigned int* __restrict__ BT) {
#pragma clang fp contract(off)
    __shared__ float sc[4];
    __shared__ float zw[LDSW];
    __shared__ unsigned int buf[2][SCB];
    int t = threadIdx.x;
    int b = blockIdx.x;
    if (t == 0) {
        float tw1 = (float)tanh((double)P[0]);
        float tw2 = (float)tanh((double)P[1]);
        sc[0] = tw1; sc[1] = tw2; sc[2] = P[2]; sc[3] = P[3];
        if (b == 0) {
            float dt1 = 1.0f - tw1 * tw1;
            float dt2 = 1.0f - tw2 * tw2;
            c[0] = tw1; c[1] = tw2; c[2] = P[2]; c[3] = P[3];
            c[4] = dt1; c[5] = dt2;
            c[6] = (-2.0f * tw1) * dt1; c[7] = (-2.0f * tw2) * dt2;
            c[8] = 2.0f * P[3];
        }
    }
    __syncthreads();
    float w1 = sc[0], w2 = sc[1], w3 = sc[2], w4 = sc[3];
    float w42 = 2.0f * w4;
    long gi = (long)b * SCB + t;
    long o = gi * 32;
    float out[32];
    if (gi == 0) {
        float h = 0.0f;
        out[0] = 0.0f;                       // Z[0]
        for (int k = 0; k < 31; ++k) {
            float x = X[k];
            float t1 = w1 * x;
            float t2 = w2 * h;
            float s1 = t1 + t2;
            float t3 = (w3 * x) * x;
            float s2 = s1 + t3;
            float t4 = (w4 * h) * h;
            h = s2 + t4;
            out[k + 1] = h;
        }
    } else {
        CHUNK55(o, out);
    }
#pragma unroll
    for (int q = 0; q < 8; ++q)
        *(float4*)(Z + o + 4 * q) = make_float4(out[4 * q], out[4 * q + 1],
                                                out[4 * q + 2], out[4 * q + 3]);
    int rbase = t * 32 + 8;
#pragma unroll
    for (int k = 0; k < 32; ++k) zw[WPAD(rbase + k)] = out[k];
    if (t == 0 && b > 0) {
        long op = (long)b * (SCB * SB) - 32;   // previous chunk owner's offset
        float pout[32];
        CHUNK55(op, pout);
#pragma unroll
        for (int q = 0; q < 7; ++q) zw[WPAD(1 + q)] = pout[25 + q];
    }
    __syncthreads();
    unsigned int m32;
    if (gi < NSB - 1) {
        float d[8]; int last[8];
#pragma unroll
        for (int g = 0; g < 8; ++g) { d[g] = 1.0f; last[g] = -g; }
        if (gi == 0) {
#pragma unroll
            for (int g = 0; g < 8; ++g) last[g] = 0;
            for (int k = 0; k < 32; ++k) {
                float fa = fabsf(w2 + w42 * zw[WPAD(rbase + k)]);
#pragma unroll
                for (int g = 0; g < 8; ++g) {
                    d[g] = d[g] * fa;
                    if (d[g] < THRESH) { last[g] = k + 1; d[g] = 1.0f; }
                }
            }
        } else {
#pragma unroll
            for (int p = 0; p < 7; ++p) {
                float fa = fabsf(w2 + w42 * zw[WPAD(rbase + p - 7)]);
#pragma unroll
                for (int g = 7 - p; g < 8; ++g) {
                    d[g] = d[g] * fa;
                    if (d[g] < THRESH) { last[g] = p - 6; d[g] = 1.0f; }
                }
            }
            for (int k = 0; k < 32; ++k) {
                float fa = fabsf(w2 + w42 * zw[WPAD(rbase + k)]);
#pragma unroll
                for (int g = 0; g < 8; ++g) {
                    d[g] = d[g] * fa;
                    if (d[g] < THRESH) { last[g] = k + 1; d[g] = 1.0f; }
                }
            }
        }
        m32 = 0;
#pragma unroll
        for (int g = 0; g < 8; ++g) {
            int delta = 32 - last[g]; if (delta > 7) delta = 7;
            m32 |= (unsigned int)delta << (3 * g);
        }
    } else {
        m32 = IDMAP;
    }
    buf[0][t] = m32;
    __syncthreads();
    int cur = 0;
    for (int off = 1; off < SCB; off <<= 1) {
        unsigned int hi = buf[cur][t];
        unsigned int r;
        if (t >= off) {
            unsigned int lo = buf[cur][t - off];
            r = 0;
#pragma unroll
            for (int g = 0; g < 8; ++g) {
                unsigned int lg = (lo >> (3 * g)) & 7u;
                r |= ((hi >> (3 * lg)) & 7u) << (3 * g);
            }
        } else {
            r = hi;
        }
        buf[cur ^ 1][t] = r;
        __syncthreads();
        cur ^= 1;
    }
    L32[gi] = buf[cur][t];
    if (t == SCB - 1) BT[b] = buf[cur][t];
}

// K2: jh with PER-LANE age replay (no serial phase-1, no ages array, 2 barriers).
// Each thread: compose g0 (wave-redundant, LDS sBT), replay decay chain from its
// subchunk's entry reset to its own q (lanes of a subchunk execute the identical
// op sequence on the same Z values -> bit-identical `last`; sequence == the
// r8-proven k_age loop continued past ci), then r13-proven JH rebuild and the
// r15-proven LDS H-exchange with dense line-grain stores.
__global__ void __launch_bounds__(256) k_jh5(const float* __restrict__ X,
                                             const float* __restrict__ Z,
                                             const float* __restrict__ c,
                                             const unsigned int* __restrict__ L32,
                                             const unsigned int* __restrict__ BT,
                                             float* __restrict__ Jout,
                                             float* __restrict__ Hout) {
#pragma clang fp contract(off)
    __shared__ unsigned int sBT[NSCB];
    __shared__ float hx[256 * 17];          // [o*17 + c], c=0..15
    int t = threadIdx.x;
    int B = blockIdx.x;
    float w2 = c[1], dt1 = c[4], dt2 = c[5], d2t1 = c[6], d2t2 = c[7], w42 = c[8];
    if (t < NSCB) sBT[t] = BT[t];
    __syncthreads();

    long q = (long)B * 256 + t;
    int i = (int)(q >> 5);                  // this output's sub-chunk
    int e = 0;
    if (i > 0) {
        int bp = (i - 1) >> 9;              // scan block of map i-1 (/ SCB)
        unsigned int g = 0;
        for (int k = 0; k < bp; ++k) g = (sBT[k] >> (3 * g)) & 7u;   // g0[bp]
        e = (int)((L32[i - 1] >> (3 * g)) & 7u);
    }
    long ci = (long)i * SB;
    long r = ci - e;
    // replay exact decay chain from the entry reset to q (k_age-sequence, per-lane)
    float d = 1.0f;
    long last = r;
    for (long m = r + 1; m <= q; ++m) {
        float av = w2 + w42 * Z[m - 1];
        d = d * fabsf(av);
        if (d < THRESH) { last = m; d = 1.0f; }
    }
    int a = (int)(q - last);

    float J0 = 0, J1 = 0, J2 = 0, J3 = 0;
    float H00 = 0, H01 = 0, H03 = 0, H11 = 0, H12 = 0, H13 = 0, H23 = 0, H33 = 0;
    if (a > 0) {
        long m0 = q - a + 1;
        {   // JH_SIMPLE(m0): fresh state after reset (round-13 proven)
            float x = X[m0 - 1];
            float h = Z[m0 - 1];
            H00 = x * d2t1; H11 = h * d2t2;
            J0 = x * dt1; J1 = h * dt2; J2 = x * x; J3 = h * h;
        }
        for (long m = m0 + 1; m <= q; ++m) {   // JH_STEP (round-13 proven)
            float x = X[m - 1];
            float h = Z[m - 1];
            float av = w2 + w42 * h;
            float g3 = 2.0f * h;
            float g1J0 = dt2 * J0, g1J1 = dt2 * J1, g1J2 = dt2 * J2, g1J3 = dt2 * J3;
            float g3J0 = g3 * J0, g3J1 = g3 * J1, g3J2 = g3 * J2, g3J3 = g3 * J3;
            float n00 = (x * d2t1) + av * H00;
            float n01 = g1J0 + av * H01;
            float n03 = g3J0 + av * H03;
            float n11 = (((h * d2t2) + g1J1) + g1J1) + av * H11;
            float n12 = g1J2 + av * H12;
            float n13 = (g1J3 + g3J1) + av * H13;
            float n23 = g3J2 + av * H23;
            float n33 = (g3J3 + g3J3) + av * H33;
            H00 = n00; H01 = n01; H03 = n03; H11 = n11;
            H12 = n12; H13 = n13; H23 = n23; H33 = n33;
            J0 = (x * dt1) + av * J0;
            J1 = (h * dt2) + av * J1;
            J2 = (x * x) + av * J2;
            J3 = (h * h) + av * J3;
        }
    }
    // J: direct store, dense (lane-consecutive 16 B)
    *((float4*)(Jout + 4 * q)) = make_float4(J0, J1, J2, J3);
    // H: stage row-major 16 values into padded LDS (r15-proven exchange)
    float* hr = hx + t * 17;
    hr[0]  = H00; hr[1]  = H01; hr[2]  = 0.0f; hr[3]  = H03;
    hr[4]  = H01; hr[5]  = H11; hr[6]  = H12;  hr[7]  = H13;
    hr[8]  = 0.0f; hr[9] = H12; hr[10] = 0.0f; hr[11] = H23;
    hr[12] = H03; hr[13] = H13; hr[14] = H23;  hr[15] = H33;
    __syncthreads();
    // dense line-grain stores: thread t emits block f4-slots t, t+256, t+512, t+768
    float4* Hp = (float4*)Hout + (long)B * 1024;
#pragma unroll
    for (int rr = 0; rr < 4; ++rr) {
        int f = 256 * rr + t;               // block-local f4 index
        int o = f >> 2;                     // output within block
        int cc = (f & 3) * 4;               // first component of this f4
        const float* s = hx + o * 17 + cc;
        Hp[f] = make_float4(s[0], s[1], s[2], s[3]);
    }
}

extern "C" void kernel_launch(void* const* d_in, const int* in_sizes, int n_in,
                              void* d_out, int out_size, void* d_ws, size_t ws_size,
                              hipStream_t stream) {
    const float* X = (const float*)d_in[0];
    const float* P = (const float*)d_in[1];
    float* out = (float*)d_out;
    float* Z = out;                       // [T]
    float* Jout = out + (long)TLEN;       // [T,4]
    float* Hout = out + 5l * TLEN;        // [T,4,4]

    char* ws = (char*)d_ws;
    float* consts = (float*)ws;                                    // @0, 64 B
    unsigned int* BT = (unsigned int*)(ws + 64);                   // 64 dwords
    unsigned int* L32 = (unsigned int*)(ws + 512);                 // 128 KB

    hipLaunchKernelGGL(k_zts, dim3(NSCB), dim3(SCB), 0, stream,
                       P, X, consts, Z, L32, BT);
    hipLaunchKernelGGL(k_jh5, dim3(TLEN / 256), dim3(256), 0, stream,
                       X, Z, consts, L32, BT, Jout, Hout);
}

// Round 17
// 40.881 us; speedup vs baseline: 1.3214x; 1.3214x over previous
//
#include <hip/hip_runtime.h>
#include <math.h>

#define TLEN (1 << 20)
#define SB 32              // reset-chain sub-chunk
#define NSB (TLEN / SB)    // 32768 sub-chunks
#define SCB 256            // maps per scan block (r10-proven compose semantics)
#define NSCB (NSB / SCB)   // 128 scan blocks
#define THRESH 1e-4f
#define IDMAP 0x00FAC688u  // packed identity map: entry g -> g (3 bits each)

#define WWORDS (SCB * SB + 8)      // 8200 staged Z words (8 lead slots)
#define WPAD(i) ((i) + ((i) >> 5)) // +1 word per 32: kills stride-32 bank conflicts
#define LDSW WPAD(WWORDS)

#pragma clang fp contract(off)

// consts layout: 0:w1 1:w2 2:w3 3:w4 4:dt1 5:dt2 6:d2t1 7:d2t2 8:2*w4

// The canonical 32-output chunk program (round-12 PROVEN, verbatim).
#define CHUNK55(OFS, OUTARR) {                                                 \
        const float4* xp_ = (const float4*)(X + (OFS) - 24);                   \
        float xa_[56];                                                         \
        _Pragma("unroll")                                                      \
        for (int q_ = 0; q_ < 14; ++q_) {                                      \
            float4 v_ = xp_[q_];                                               \
            xa_[4 * q_ + 0] = v_.x; xa_[4 * q_ + 1] = v_.y;                    \
            xa_[4 * q_ + 2] = v_.z; xa_[4 * q_ + 3] = v_.w;                    \
        }                                                                      \
        float h_ = 0.0f;                                                       \
        _Pragma("unroll")                                                      \
        for (int p_ = 0; p_ < 55; ++p_) {                                      \
            float x_ = xa_[p_];                                                \
            float t1_ = w1 * x_;                                               \
            float t2_ = w2 * h_;                                               \
            float s1_ = t1_ + t2_;                                             \
            float t3_ = (w3 * x_) * x_;                                        \
            float s2_ = s1_ + t3_;                                             \
            float t4_ = (w4 * h_) * h_;                                        \
            h_ = s2_ + t4_;                                                    \
            if (p_ >= 23) OUTARR[p_ - 23] = h_;                                \
        }                                                                      \
    }

// K1: Z + tables + scan (r12-proven bodies; SCB=256 -> 128 blocks, 2x CU use).
__global__ void __launch_bounds__(256) k_zts(const float* __restrict__ P,
                                             const float* __restrict__ X,
                                             float* __restrict__ c,
                                             float* __restrict__ Z,
                                             unsigned int* __restrict__ L32,
                                             unsigned int* __restrict__ BT) {
#pragma clang fp contract(off)
    __shared__ float sc[4];
    __shared__ float zw[LDSW];
    __shared__ unsigned int buf[2][SCB];
    int t = threadIdx.x;
    int b = blockIdx.x;
    if (t == 0) {
        float tw1 = (float)tanh((double)P[0]);
        float tw2 = (float)tanh((double)P[1]);
        sc[0] = tw1; sc[1] = tw2; sc[2] = P[2]; sc[3] = P[3];
        if (b == 0) {
            float dt1 = 1.0f - tw1 * tw1;
            float dt2 = 1.0f - tw2 * tw2;
            c[0] = tw1; c[1] = tw2; c[2] = P[2]; c[3] = P[3];
            c[4] = dt1; c[5] = dt2;
            c[6] = (-2.0f * tw1) * dt1; c[7] = (-2.0f * tw2) * dt2;
            c[8] = 2.0f * P[3];
        }
    }
    __syncthreads();
    float w1 = sc[0], w2 = sc[1], w3 = sc[2], w4 = sc[3];
    float w42 = 2.0f * w4;
    long gi = (long)b * SCB + t;
    long o = gi * 32;
    float out[32];
    if (gi == 0) {
        float h = 0.0f;
        out[0] = 0.0f;                       // Z[0]
        for (int k = 0; k < 31; ++k) {
            float x = X[k];
            float t1 = w1 * x;
            float t2 = w2 * h;
            float s1 = t1 + t2;
            float t3 = (w3 * x) * x;
            float s2 = s1 + t3;
            float t4 = (w4 * h) * h;
            h = s2 + t4;
            out[k + 1] = h;
        }
    } else {
        CHUNK55(o, out);
    }
#pragma unroll
    for (int q = 0; q < 8; ++q)
        *(float4*)(Z + o + 4 * q) = make_float4(out[4 * q], out[4 * q + 1],
                                                out[4 * q + 2], out[4 * q + 3]);
    int rbase = t * 32 + 8;
#pragma unroll
    for (int k = 0; k < 32; ++k) zw[WPAD(rbase + k)] = out[k];
    if (t == 0 && b > 0) {
        long op = (long)b * (SCB * SB) - 32;   // previous chunk owner's offset
        float pout[32];
        CHUNK55(op, pout);
#pragma unroll
        for (int q = 0; q < 7; ++q) zw[WPAD(1 + q)] = pout[25 + q];
    }
    __syncthreads();
    unsigned int m32;
    if (gi < NSB - 1) {
        float d[8]; int last[8];
#pragma unroll
        for (int g = 0; g < 8; ++g) { d[g] = 1.0f; last[g] = -g; }
        if (gi == 0) {
#pragma unroll
            for (int g = 0; g < 8; ++g) last[g] = 0;
            for (int k = 0; k < 32; ++k) {
                float fa = fabsf(w2 + w42 * zw[WPAD(rbase + k)]);
#pragma unroll
                for (int g = 0; g < 8; ++g) {
                    d[g] = d[g] * fa;
                    if (d[g] < THRESH) { last[g] = k + 1; d[g] = 1.0f; }
                }
            }
        } else {
#pragma unroll
            for (int p = 0; p < 7; ++p) {
                float fa = fabsf(w2 + w42 * zw[WPAD(rbase + p - 7)]);
#pragma unroll
                for (int g = 7 - p; g < 8; ++g) {
                    d[g] = d[g] * fa;
                    if (d[g] < THRESH) { last[g] = p - 6; d[g] = 1.0f; }
                }
            }
            for (int k = 0; k < 32; ++k) {
                float fa = fabsf(w2 + w42 * zw[WPAD(rbase + k)]);
#pragma unroll
                for (int g = 0; g < 8; ++g) {
                    d[g] = d[g] * fa;
                    if (d[g] < THRESH) { last[g] = k + 1; d[g] = 1.0f; }
                }
            }
        }
        m32 = 0;
#pragma unroll
        for (int g = 0; g < 8; ++g) {
            int delta = 32 - last[g]; if (delta > 7) delta = 7;
            m32 |= (unsigned int)delta << (3 * g);
        }
    } else {
        m32 = IDMAP;
    }
    buf[0][t] = m32;
    __syncthreads();
    int cur = 0;
    for (int off = 1; off < SCB; off <<= 1) {
        unsigned int hi = buf[cur][t];
        unsigned int r;
        if (t >= off) {
            unsigned int lo = buf[cur][t - off];
            r = 0;
#pragma unroll
            for (int g = 0; g < 8; ++g) {
                unsigned int lg = (lo >> (3 * g)) & 7u;
                r |= ((hi >> (3 * lg)) & 7u) << (3 * g);
            }
        } else {
            r = hi;
        }
        buf[cur ^ 1][t] = r;
        __syncthreads();
        cur ^= 1;
    }
    L32[gi] = buf[cur][t];
    if (t == SCB - 1) BT[b] = buf[cur][t];
}

// K2: r15-PROVEN structure (8-thread phase-1 age replay, LDS H-exchange, dense
// line-grain stores) + LDS-staged X/Z windows so all chain reads are local.
// bp/compose use SCB=256 semantics (r10-proven).
__global__ void __launch_bounds__(256) k_jh6(const float* __restrict__ X,
                                             const float* __restrict__ Z,
                                             const float* __restrict__ c,
                                             const unsigned int* __restrict__ L32,
                                             const unsigned int* __restrict__ BT,
                                             float* __restrict__ Jout,
                                             float* __restrict__ Hout) {
#pragma clang fp contract(off)
    __shared__ unsigned int sBT[NSCB];
    __shared__ unsigned char ages[256];
    __shared__ float zs[264];               // Z[B*256-8 .. B*256+255]
    __shared__ float xs[264];               // X[B*256-8 .. B*256+255]
    __shared__ float hx[256 * 17];          // [o*17 + cmp], cmp=0..15
    int t = threadIdx.x;
    int B = blockIdx.x;
    float w2 = c[1], dt1 = c[4], dt2 = c[5], d2t1 = c[6], d2t2 = c[7], w42 = c[8];
    long base = (long)B * 256 - 8;          // f4-aligned window start
    if (t < NSCB) sBT[t] = BT[t];
    if (t >= 128 && t < 194) {              // 66 f4s of Z
        int s = t - 128;
        long zi = base + 4l * s;
        float4 v = make_float4(0.f, 0.f, 0.f, 0.f);
        if (zi >= 0) v = *(const float4*)(Z + zi);
        zs[4 * s] = v.x; zs[4 * s + 1] = v.y; zs[4 * s + 2] = v.z; zs[4 * s + 3] = v.w;
    } else if (t >= 194 && t < 260 - 0 && t < 256) {  // 62 f4s of X (t=194..255)
        int s = t - 194;
        long zi = base + 4l * s;
        float4 v = make_float4(0.f, 0.f, 0.f, 0.f);
        if (zi >= 0) v = *(const float4*)(X + zi);
        xs[4 * s] = v.x; xs[4 * s + 1] = v.y; xs[4 * s + 2] = v.z; xs[4 * s + 3] = v.w;
    } else if (t >= 64 && t < 68) {          // remaining 4 f4s of X (s=62..65)
        int s = t - 64 + 62;
        long zi = base + 4l * s;
        float4 v = make_float4(0.f, 0.f, 0.f, 0.f);
        if (zi >= 0) v = *(const float4*)(X + zi);
        xs[4 * s] = v.x; xs[4 * s + 1] = v.y; xs[4 * s + 2] = v.z; xs[4 * s + 3] = v.w;
    }
    __syncthreads();
    if (t < 8) {                             // r15-proven phase-1, reads from LDS
        int i = B * 8 + t;
        int e = 0;
        if (i > 0) {
            int bp = (i - 1) >> 8;           // / SCB (=256)
            unsigned int g = 0;
            for (int k = 0; k < bp; ++k) g = (sBT[k] >> (3 * g)) & 7u;
            e = (int)((L32[i - 1] >> (3 * g)) & 7u);
        }
        long ci = (long)i * SB;
        long r = ci - e;
        float d = 1.0f;
        long last = r;
        for (long m = r + 1; m <= ci; ++m) {
            float a = w2 + w42 * zs[(int)(m - 1 - base)];
            d = d * fabsf(a);
            if (d < THRESH) { last = m; d = 1.0f; }
        }
        ages[t * 32] = (unsigned char)(ci - last);
        for (int k = 1; k < SB; ++k) {
            long m = ci + k;
            float a = w2 + w42 * zs[(int)(m - 1 - base)];
            d = d * fabsf(a);
            if (d < THRESH) { last = m; d = 1.0f; }
            ages[t * 32 + k] = (unsigned char)(m - last);
        }
    }
    __syncthreads();
    long q = (long)B * 256 + t;
    int a = (int)ages[t];
    float J0 = 0, J1 = 0, J2 = 0, J3 = 0;
    float H00 = 0, H01 = 0, H03 = 0, H11 = 0, H12 = 0, H13 = 0, H23 = 0, H33 = 0;
    if (a > 0) {
        long m0 = q - a + 1;
        {   // JH_SIMPLE (r13-proven), LDS operands
            int ix = (int)(m0 - 1 - base);
            float x = xs[ix];
            float h = zs[ix];
            H00 = x * d2t1; H11 = h * d2t2;
            J0 = x * dt1; J1 = h * dt2; J2 = x * x; J3 = h * h;
        }
        for (long m = m0 + 1; m <= q; ++m) {   // JH_STEP (r13-proven), LDS operands
            int ix = (int)(m - 1 - base);
            float x = xs[ix];
            float h = zs[ix];
            float av = w2 + w42 * h;
            float g3 = 2.0f * h;
            float g1J0 = dt2 * J0, g1J1 = dt2 * J1, g1J2 = dt2 * J2, g1J3 = dt2 * J3;
            float g3J0 = g3 * J0, g3J1 = g3 * J1, g3J2 = g3 * J2, g3J3 = g3 * J3;
            float n00 = (x * d2t1) + av * H00;
            float n01 = g1J0 + av * H01;
            float n03 = g3J0 + av * H03;
            float n11 = (((h * d2t2) + g1J1) + g1J1) + av * H11;
            float n12 = g1J2 + av * H12;
            float n13 = (g1J3 + g3J1) + av * H13;
            float n23 = g3J2 + av * H23;
            float n33 = (g3J3 + g3J3) + av * H33;
            H00 = n00; H01 = n01; H03 = n03; H11 = n11;
            H12 = n12; H13 = n13; H23 = n23; H33 = n33;
            J0 = (x * dt1) + av * J0;
            J1 = (h * dt2) + av * J1;
            J2 = (x * x) + av * J2;
            J3 = (h * h) + av * J3;
        }
    }
    // J: direct store, dense (lane-consecutive 16 B)
    *((float4*)(Jout + 4 * q)) = make_float4(J0, J1, J2, J3);
    // H: stage into padded LDS (r15-proven exchange)
    float* hr = hx + t * 17;
    hr[0]  = H00; hr[1]  = H01; hr[2]  = 0.0f; hr[3]  = H03;
    hr[4]  = H01; hr[5]  = H11; hr[6]  = H12;  hr[7]  = H13;
    hr[8]  = 0.0f; hr[9] = H12; hr[10] = 0.0f; hr[11] = H23;
    hr[12] = H03; hr[13] = H13; hr[14] = H23;  hr[15] = H33;
    __syncthreads();
    float4* Hp = (float4*)Hout + (long)B * 1024;
#pragma unroll
    for (int rr = 0; rr < 4; ++rr) {
        int f = 256 * rr + t;               // block-local f4 index
        int o = f >> 2;                     // output within block
        int cc = (f & 3) * 4;               // first component of this f4
        const float* s = hx + o * 17 + cc;
        Hp[f] = make_float4(s[0], s[1], s[2], s[3]);
    }
}

extern "C" void kernel_launch(void* const* d_in, const int* in_sizes, int n_in,
                              void* d_out, int out_size, void* d_ws, size_t ws_size,
                              hipStream_t stream) {
    const float* X = (const float*)d_in[0];
    const float* P = (const float*)d_in[1];
    float* out = (float*)d_out;
    float* Z = out;                       // [T]
    float* Jout = out + (long)TLEN;       // [T,4]
    float* Hout = out + 5l * TLEN;        // [T,4,4]

    char* ws = (char*)d_ws;
    float* consts = (float*)ws;                                    // @0, 64 B
    unsigned int* BT = (unsigned int*)(ws + 64);                   // 128 dwords
    unsigned int* L32 = (unsigned int*)(ws + 1024);                // 128 KB

    hipLaunchKernelGGL(k_zts, dim3(NSCB), dim3(SCB), 0, stream,
                       P, X, consts, Z, L32, BT);
    hipLaunchKernelGGL(k_jh6, dim3(TLEN / 256), dim3(256), 0, stream,
                       X, Z, consts, L32, BT, Jout, Hout);
}

// Round 18
// 40.733 us; speedup vs baseline: 1.3262x; 1.0036x over previous
//
#include <hip/hip_runtime.h>
#include <math.h>

#define TLEN (1 << 20)
#define SB 32              // reset-chain sub-chunk
#define NSB (TLEN / SB)    // 32768 sub-chunks
#define SCB 256            // maps per scan block
#define NSCB (NSB / SCB)   // 128 scan blocks
#define THRESH 1e-4f
#define IDMAP 0x00FAC688u  // packed identity map: entry g -> g (3 bits each)

#define WWORDS (SCB * SB + 8)      // 8200 staged Z words (8 lead slots)
#define WPAD(i) ((i) + ((i) >> 5)) // +1 word per 32: kills stride-32 bank conflicts
#define LDSW WPAD(WWORDS)

#pragma clang fp contract(off)

// consts layout: 0:w1 1:w2 2:w3 3:w4 4:dt1 5:dt2 6:d2t1 7:d2t2 8:2*w4

// The canonical 32-output chunk program (round-12 PROVEN, verbatim).
#define CHUNK55(OFS, OUTARR) {                                                 \
        const float4* xp_ = (const float4*)(X + (OFS) - 24);                   \
        float xa_[56];                                                         \
        _Pragma("unroll")                                                      \
        for (int q_ = 0; q_ < 14; ++q_) {                                      \
            float4 v_ = xp_[q_];                                               \
            xa_[4 * q_ + 0] = v_.x; xa_[4 * q_ + 1] = v_.y;                    \
            xa_[4 * q_ + 2] = v_.z; xa_[4 * q_ + 3] = v_.w;                    \
        }                                                                      \
        float h_ = 0.0f;                                                       \
        _Pragma("unroll")                                                      \
        for (int p_ = 0; p_ < 55; ++p_) {                                      \
            float x_ = xa_[p_];                                                \
            float t1_ = w1 * x_;                                               \
            float t2_ = w2 * h_;                                               \
            float s1_ = t1_ + t2_;                                             \
            float t3_ = (w3 * x_) * x_;                                        \
            float s2_ = s1_ + t3_;                                             \
            float t4_ = (w4 * h_) * h_;                                        \
            h_ = s2_ + t4_;                                                    \
            if (p_ >= 23) OUTARR[p_ - 23] = h_;                                \
        }                                                                      \
    }

// K1: Z + tables + scan + RESET MASKS. Chain math r12-proven verbatim; masks are
// the same d[g]<THRESH predicates captured as bits (exact by construction).
__global__ void __launch_bounds__(256) k_zts(const float* __restrict__ P,
                                             const float* __restrict__ X,
                                             float* __restrict__ c,
                                             float* __restrict__ Z,
                                             unsigned int* __restrict__ L32,
                                             unsigned int* __restrict__ BT,
                                             unsigned int* __restrict__ Msk) {
#pragma clang fp contract(off)
    __shared__ float sc[4];
    __shared__ float zw[LDSW];
    __shared__ unsigned int buf[2][SCB];
    int t = threadIdx.x;
    int b = blockIdx.x;
    if (t == 0) {
        float tw1 = (float)tanh((double)P[0]);
        float tw2 = (float)tanh((double)P[1]);
        sc[0] = tw1; sc[1] = tw2; sc[2] = P[2]; sc[3] = P[3];
        if (b == 0) {
            float dt1 = 1.0f - tw1 * tw1;
            float dt2 = 1.0f - tw2 * tw2;
            c[0] = tw1; c[1] = tw2; c[2] = P[2]; c[3] = P[3];
            c[4] = dt1; c[5] = dt2;
            c[6] = (-2.0f * tw1) * dt1; c[7] = (-2.0f * tw2) * dt2;
            c[8] = 2.0f * P[3];
        }
    }
    __syncthreads();
    float w1 = sc[0], w2 = sc[1], w3 = sc[2], w4 = sc[3];
    float w42 = 2.0f * w4;
    long gi = (long)b * SCB + t;
    long o = gi * 32;
    float out[32];
    if (gi == 0) {
        float h = 0.0f;
        out[0] = 0.0f;                       // Z[0]
        for (int k = 0; k < 31; ++k) {
            float x = X[k];
            float t1 = w1 * x;
            float t2 = w2 * h;
            float s1 = t1 + t2;
            float t3 = (w3 * x) * x;
            float s2 = s1 + t3;
            float t4 = (w4 * h) * h;
            h = s2 + t4;
            out[k + 1] = h;
        }
    } else {
        CHUNK55(o, out);
    }
#pragma unroll
    for (int q = 0; q < 8; ++q)
        *(float4*)(Z + o + 4 * q) = make_float4(out[4 * q], out[4 * q + 1],
                                                out[4 * q + 2], out[4 * q + 3]);
    int rbase = t * 32 + 8;
#pragma unroll
    for (int k = 0; k < 32; ++k) zw[WPAD(rbase + k)] = out[k];
    if (t == 0 && b > 0) {
        long op = (long)b * (SCB * SB) - 32;   // previous chunk owner's offset
        float pout[32];
        CHUNK55(op, pout);
#pragma unroll
        for (int q = 0; q < 7; ++q) zw[WPAD(1 + q)] = pout[25 + q];
    }
    __syncthreads();
    // ---- chains for ALL sub-chunks (maps + reset masks) ----
    unsigned int m32;
    unsigned int msk[8];
    {
        float d[8]; int last[8];
#pragma unroll
        for (int g = 0; g < 8; ++g) { d[g] = 1.0f; last[g] = -g; msk[g] = 0u; }
        if (gi == 0) {
#pragma unroll
            for (int g = 0; g < 8; ++g) last[g] = 0;
            for (int k = 0; k < 32; ++k) {
                float fa = fabsf(w2 + w42 * zw[WPAD(rbase + k)]);
#pragma unroll
                for (int g = 0; g < 8; ++g) {
                    d[g] = d[g] * fa;
                    if (d[g] < THRESH) { last[g] = k + 1; d[g] = 1.0f; msk[g] |= 1u << k; }
                }
            }
        } else {
#pragma unroll
            for (int p = 0; p < 7; ++p) {   // lead-in: pre-chunk, no mask bits
                float fa = fabsf(w2 + w42 * zw[WPAD(rbase + p - 7)]);
#pragma unroll
                for (int g = 7 - p; g < 8; ++g) {
                    d[g] = d[g] * fa;
                    if (d[g] < THRESH) { last[g] = p - 6; d[g] = 1.0f; }
                }
            }
            for (int k = 0; k < 32; ++k) {
                float fa = fabsf(w2 + w42 * zw[WPAD(rbase + k)]);
#pragma unroll
                for (int g = 0; g < 8; ++g) {
                    d[g] = d[g] * fa;
                    if (d[g] < THRESH) { last[g] = k + 1; d[g] = 1.0f; msk[g] |= 1u << k; }
                }
            }
        }
        if (gi < NSB - 1) {
            m32 = 0;
#pragma unroll
            for (int g = 0; g < 8; ++g) {
                int delta = 32 - last[g]; if (delta > 7) delta = 7;
                m32 |= (unsigned int)delta << (3 * g);
            }
        } else {
            m32 = IDMAP;
        }
    }
    uint4* mp = (uint4*)Msk + gi * 2;
    mp[0] = make_uint4(msk[0], msk[1], msk[2], msk[3]);
    mp[1] = make_uint4(msk[4], msk[5], msk[6], msk[7]);
    // ---- scan (r12-proven body, verbatim) ----
    buf[0][t] = m32;
    __syncthreads();
    int cur = 0;
    for (int off = 1; off < SCB; off <<= 1) {
        unsigned int hi = buf[cur][t];
        unsigned int r;
        if (t >= off) {
            unsigned int lo = buf[cur][t - off];
            r = 0;
#pragma unroll
            for (int g = 0; g < 8; ++g) {
                unsigned int lg = (lo >> (3 * g)) & 7u;
                r |= ((hi >> (3 * lg)) & 7u) << (3 * g);
            }
        } else {
            r = hi;
        }
        buf[cur ^ 1][t] = r;
        __syncthreads();
        cur ^= 1;
    }
    L32[gi] = buf[cur][t];
    if (t == SCB - 1) BT[b] = buf[cur][t];
}

// K2: jh with mask-decoded ages (no phase-1 Z replay). Stage sBT/zs/xs/masks;
// 8 threads compose entry gaps only; every thread decodes its age in ~5 ops,
// then r13-proven JH rebuild + r15-proven LDS H-exchange + dense stores.
__global__ void __launch_bounds__(256) k_jh7(const float* __restrict__ X,
                                             const float* __restrict__ Z,
                                             const float* __restrict__ c,
                                             const unsigned int* __restrict__ L32,
                                             const unsigned int* __restrict__ BT,
                                             const unsigned int* __restrict__ Msk,
                                             float* __restrict__ Jout,
                                             float* __restrict__ Hout) {
#pragma clang fp contract(off)
    __shared__ unsigned int sBT[NSCB];
    __shared__ unsigned int smsk[64];       // 8 sub-chunks x 8 entry gaps
    __shared__ unsigned char eL[8];
    __shared__ float zs[264];               // Z[B*256-8 .. B*256+255]
    __shared__ float xs[264];               // X[B*256-8 .. B*256+255]
    __shared__ float hx[256 * 17];          // [o*17 + cmp], cmp=0..15
    int t = threadIdx.x;
    int B = blockIdx.x;
    float w2 = c[1], dt1 = c[4], dt2 = c[5], d2t1 = c[6], d2t2 = c[7], w42 = c[8];
    long base = (long)B * 256 - 8;          // f4-aligned window start
    if (t < NSCB) sBT[t] = BT[t];
    if (t < 16) {                            // stage this block's 64 mask words
        uint4 v = ((const uint4*)Msk)[(long)B * 16 + t];
        smsk[4 * t] = v.x; smsk[4 * t + 1] = v.y;
        smsk[4 * t + 2] = v.z; smsk[4 * t + 3] = v.w;
    }
    if (t >= 128 && t < 194) {              // 66 f4s of Z
        int s = t - 128;
        long zi = base + 4l * s;
        float4 v = make_float4(0.f, 0.f, 0.f, 0.f);
        if (zi >= 0) v = *(const float4*)(Z + zi);
        zs[4 * s] = v.x; zs[4 * s + 1] = v.y; zs[4 * s + 2] = v.z; zs[4 * s + 3] = v.w;
    } else if (t >= 194 && t < 256) {       // 62 f4s of X (t=194..255)
        int s = t - 194;
        long zi = base + 4l * s;
        float4 v = make_float4(0.f, 0.f, 0.f, 0.f);
        if (zi >= 0) v = *(const float4*)(X + zi);
        xs[4 * s] = v.x; xs[4 * s + 1] = v.y; xs[4 * s + 2] = v.z; xs[4 * s + 3] = v.w;
    } else if (t >= 64 && t < 68) {          // remaining 4 f4s of X (s=62..65)
        int s = t - 64 + 62;
        long zi = base + 4l * s;
        float4 v = make_float4(0.f, 0.f, 0.f, 0.f);
        if (zi >= 0) v = *(const float4*)(X + zi);
        xs[4 * s] = v.x; xs[4 * s + 1] = v.y; xs[4 * s + 2] = v.z; xs[4 * s + 3] = v.w;
    }
    __syncthreads();
    if (t < 8) {                             // entry-gap compose only (no Z replay)
        int i = B * 8 + t;
        int e = 0;
        if (i > 0) {
            int bp = (i - 1) >> 8;           // / SCB (=256)
            unsigned int g = 0;
            for (int k = 0; k < bp; ++k) g = (sBT[k] >> (3 * g)) & 7u;
            e = (int)((L32[i - 1] >> (3 * g)) & 7u);
        }
        eL[t] = (unsigned char)e;
    }
    __syncthreads();
    long q = (long)B * 256 + t;
    int il = t >> 5;                         // sub-chunk within block (0..7)
    int j = t & 31;                          // position within sub-chunk
    int e = (int)eL[il];
    unsigned int mask = smsk[il * 8 + e];
    unsigned int bits = mask & ((j > 0) ? ((1u << j) - 1u) : 0u);
    int a = bits ? (j + __clz(bits) - 32) : (j + e);

    float J0 = 0, J1 = 0, J2 = 0, J3 = 0;
    float H00 = 0, H01 = 0, H03 = 0, H11 = 0, H12 = 0, H13 = 0, H23 = 0, H33 = 0;
    if (a > 0) {
        long m0 = q - a + 1;
        {   // JH_SIMPLE (r13-proven), LDS operands
            int ix = (int)(m0 - 1 - base);
            float x = xs[ix];
            float h = zs[ix];
            H00 = x * d2t1; H11 = h * d2t2;
            J0 = x * dt1; J1 = h * dt2; J2 = x * x; J3 = h * h;
        }
        for (long m = m0 + 1; m <= q; ++m) {   // JH_STEP (r13-proven), LDS operands
            int ix = (int)(m - 1 - base);
            float x = xs[ix];
            float h = zs[ix];
            float av = w2 + w42 * h;
            float g3 = 2.0f * h;
            float g1J0 = dt2 * J0, g1J1 = dt2 * J1, g1J2 = dt2 * J2, g1J3 = dt2 * J3;
            float g3J0 = g3 * J0, g3J1 = g3 * J1, g3J2 = g3 * J2, g3J3 = g3 * J3;
            float n00 = (x * d2t1) + av * H00;
            float n01 = g1J0 + av * H01;
            float n03 = g3J0 + av * H03;
            float n11 = (((h * d2t2) + g1J1) + g1J1) + av * H11;
            float n12 = g1J2 + av * H12;
            float n13 = (g1J3 + g3J1) + av * H13;
            float n23 = g3J2 + av * H23;
            float n33 = (g3J3 + g3J3) + av * H33;
            H00 = n00; H01 = n01; H03 = n03; H11 = n11;
            H12 = n12; H13 = n13; H23 = n23; H33 = n33;
            J0 = (x * dt1) + av * J0;
            J1 = (h * dt2) + av * J1;
            J2 = (x * x) + av * J2;
            J3 = (h * h) + av * J3;
        }
    }
    // J: direct store, dense (lane-consecutive 16 B)
    *((float4*)(Jout + 4 * q)) = make_float4(J0, J1, J2, J3);
    // H: stage into padded LDS (r15-proven exchange)
    float* hr = hx + t * 17;
    hr[0]  = H00; hr[1]  = H01; hr[2]  = 0.0f; hr[3]  = H03;
    hr[4]  = H01; hr[5]  = H11; hr[6]  = H12;  hr[7]  = H13;
    hr[8]  = 0.0f; hr[9] = H12; hr[10] = 0.0f; hr[11] = H23;
    hr[12] = H03; hr[13] = H13; hr[14] = H23;  hr[15] = H33;
    __syncthreads();
    float4* Hp = (float4*)Hout + (long)B * 1024;
#pragma unroll
    for (int rr = 0; rr < 4; ++rr) {
        int f = 256 * rr + t;               // block-local f4 index
        int o = f >> 2;                     // output within block
        int cc = (f & 3) * 4;               // first component of this f4
        const float* s = hx + o * 17 + cc;
        Hp[f] = make_float4(s[0], s[1], s[2], s[3]);
    }
}

extern "C" void kernel_launch(void* const* d_in, const int* in_sizes, int n_in,
                              void* d_out, int out_size, void* d_ws, size_t ws_size,
                              hipStream_t stream) {
    const float* X = (const float*)d_in[0];
    const float* P = (const float*)d_in[1];
    float* out = (float*)d_out;
    float* Z = out;                       // [T]
    float* Jout = out + (long)TLEN;       // [T,4]
    float* Hout = out + 5l * TLEN;        // [T,4,4]

    char* ws = (char*)d_ws;
    float* consts = (float*)ws;                                    // @0, 64 B
    unsigned int* BT = (unsigned int*)(ws + 64);                   // 128 dwords
    unsigned int* L32 = (unsigned int*)(ws + 1024);                // 128 KB
    unsigned int* Msk = (unsigned int*)(ws + 1024 + (size_t)NSB * 4);  // 1 MB

    hipLaunchKernelGGL(k_zts, dim3(NSCB), dim3(SCB), 0, stream,
                       P, X, consts, Z, L32, BT, Msk);
    hipLaunchKernelGGL(k_jh7, dim3(TLEN / 256), dim3(256), 0, stream,
                       X, Z, consts, L32, BT, Msk, Jout, Hout);
}

// Round 19
// 40.067 us; speedup vs baseline: 1.3482x; 1.0166x over previous
//
#include <hip/hip_runtime.h>
#include <math.h>

#define TLEN (1 << 20)
#define SB 32              // reset-chain sub-chunk
#define NSB (TLEN / SB)    // 32768 sub-chunks
#define SCB 256            // maps per scan block
#define NSCB (NSB / SCB)   // 128 scan blocks
#define THRESH 1e-4f
#define IDMAP 0x00FAC688u  // packed identity map: entry g -> g (3 bits each)

#pragma clang fp contract(off)

// consts layout: 0:w1 1:w2 2:w3 3:w4 4:dt1 5:dt2 6:d2t1 7:d2t2 8:2*w4

// K1: h (=Z), round-11 PROVEN verbatim (float4 loads, unrolled 31-step chain).
__global__ void __launch_bounds__(256) k_hscan(const float* __restrict__ P,
                                               const float* __restrict__ X,
                                               float* __restrict__ c,
                                               float* __restrict__ Z) {
#pragma clang fp contract(off)
    __shared__ float sc[4];
    if (threadIdx.x == 0) {
        float w1 = (float)tanh((double)P[0]);
        float w2 = (float)tanh((double)P[1]);
        sc[0] = w1; sc[1] = w2; sc[2] = P[2]; sc[3] = P[3];
        if (blockIdx.x == 0) {
            float dt1 = 1.0f - w1 * w1;
            float dt2 = 1.0f - w2 * w2;
            c[0] = w1; c[1] = w2; c[2] = P[2]; c[3] = P[3];
            c[4] = dt1; c[5] = dt2;
            c[6] = (-2.0f * w1) * dt1; c[7] = (-2.0f * w2) * dt2;
            c[8] = 2.0f * P[3];
        }
    }
    __syncthreads();
    float w1 = sc[0], w2 = sc[1], w3 = sc[2], w4 = sc[3];
    long j = blockIdx.x * (long)blockDim.x + threadIdx.x;
    long o = j * 8;
    if (j >= 3) {
        const float4* xp = (const float4*)(X + o - 24);
        float xa[32];
#pragma unroll
        for (int q = 0; q < 8; ++q) {
            float4 v = xp[q];
            xa[4 * q + 0] = v.x; xa[4 * q + 1] = v.y;
            xa[4 * q + 2] = v.z; xa[4 * q + 3] = v.w;
        }
        float h = 0.0f;
        float out[8];
#pragma unroll
        for (int p = 0; p < 31; ++p) {
            float x = xa[p];
            float t1 = w1 * x;
            float t2 = w2 * h;
            float s1 = t1 + t2;
            float t3 = (w3 * x) * x;
            float s2 = s1 + t3;
            float t4 = (w4 * h) * h;
            h = s2 + t4;
            if (p >= 23) out[p - 23] = h;
        }
        *(float4*)(Z + o) = make_float4(out[0], out[1], out[2], out[3]);
        *(float4*)(Z + o + 4) = make_float4(out[4], out[5], out[6], out[7]);
    } else {
        long b = o - 24; if (b < 0) b = 0;
        long tend = o + 7;
        float h = 0.0f;
        if (o == 0) Z[0] = 0.0f;
        for (long t = b; t < tend; ++t) {
            float x = X[t];
            float t1 = w1 * x;
            float t2 = w2 * h;
            float s1 = t1 + t2;
            float t3 = (w3 * x) * x;
            float s2 = s1 + t3;
            float t4 = (w4 * h) * h;
            h = s2 + t4;
            if (t + 1 >= o) Z[t + 1] = h;
        }
    }
}

// K2: tables + reset masks, gap-per-thread (round-5 PROVEN chain; mask bits are
// the same d<THRESH predicates for in-chunk steps). 262144 threads, reads Z.
__global__ void __launch_bounds__(256) k_tabm(const float* __restrict__ c,
                                              const float* __restrict__ Z,
                                              unsigned int* __restrict__ tab32,
                                              unsigned int* __restrict__ Msk) {
#pragma clang fp contract(off)
    long tid = blockIdx.x * (long)blockDim.x + threadIdx.x;
    if (tid >= (long)NSB * 8) return;
    int i = (int)(tid >> 3);
    int g = (int)(tid & 7);
    float w2 = c[1], w42 = c[8];
    long ci = (long)i * SB;
    long start = ci - g; if (start < 0) start = 0;
    long end = ci + SB;
    float d = 1.0f;
    long last = start;
    unsigned int msk = 0u;
    for (long m = start + 1; m <= end; ++m) {
        float a = w2 + w42 * Z[m - 1];
        d = d * fabsf(a);
        if (d < THRESH) {
            last = m; d = 1.0f;
            if (m > ci) msk |= 1u << (int)(m - ci - 1);
        }
    }
    Msk[(long)i * 8 + g] = msk;
    if (i < NSB - 1) {
        long delta = end - last; if (delta > 7) delta = 7;   // provably never clamps
        unsigned int v = (unsigned int)delta << (3 * g);
        v |= __shfl_xor(v, 1);
        v |= __shfl_xor(v, 2);
        v |= __shfl_xor(v, 4);
        if (g == 0) tab32[i] = v;
    }
}

// K3: Hillis-Steele scan over packed maps (round-5/10 PROVEN, SCB=256).
__global__ void __launch_bounds__(256) k_scanA(const unsigned int* __restrict__ tab32,
                                               unsigned int* __restrict__ L32,
                                               unsigned int* __restrict__ BT) {
    __shared__ unsigned int buf[2][SCB];
    int t = threadIdx.x;
    long gi = (long)blockIdx.x * SCB + t;
    buf[0][t] = (gi < NSB - 1) ? tab32[gi] : IDMAP;
    __syncthreads();
    int cur = 0;
    for (int off = 1; off < SCB; off <<= 1) {
        unsigned int hi = buf[cur][t];
        unsigned int r;
        if (t >= off) {
            unsigned int lo = buf[cur][t - off];
            r = 0;
#pragma unroll
            for (int g = 0; g < 8; ++g) {
                unsigned int lg = (lo >> (3 * g)) & 7u;
                r |= ((hi >> (3 * lg)) & 7u) << (3 * g);
            }
        } else {
            r = hi;
        }
        buf[cur ^ 1][t] = r;
        __syncthreads();
        cur ^= 1;
    }
    L32[gi] = buf[cur][t];
    if (t == SCB - 1) BT[blockIdx.x] = buf[cur][t];
}

// K4: jh with mask-decoded ages (round-18 PROVEN, verbatim).
__global__ void __launch_bounds__(256) k_jh7(const float* __restrict__ X,
                                             const float* __restrict__ Z,
                                             const float* __restrict__ c,
                                             const unsigned int* __restrict__ L32,
                                             const unsigned int* __restrict__ BT,
                                             const unsigned int* __restrict__ Msk,
                                             float* __restrict__ Jout,
                                             float* __restrict__ Hout) {
#pragma clang fp contract(off)
    __shared__ unsigned int sBT[NSCB];
    __shared__ unsigned int smsk[64];       // 8 sub-chunks x 8 entry gaps
    __shared__ unsigned char eL[8];
    __shared__ float zs[264];               // Z[B*256-8 .. B*256+255]
    __shared__ float xs[264];               // X[B*256-8 .. B*256+255]
    __shared__ float hx[256 * 17];          // [o*17 + cmp], cmp=0..15
    int t = threadIdx.x;
    int B = blockIdx.x;
    float w2 = c[1], dt1 = c[4], dt2 = c[5], d2t1 = c[6], d2t2 = c[7], w42 = c[8];
    long base = (long)B * 256 - 8;          // f4-aligned window start
    if (t < NSCB) sBT[t] = BT[t];
    if (t < 16) {                            // stage this block's 64 mask words
        uint4 v = ((const uint4*)Msk)[(long)B * 16 + t];
        smsk[4 * t] = v.x; smsk[4 * t + 1] = v.y;
        smsk[4 * t + 2] = v.z; smsk[4 * t + 3] = v.w;
    }
    if (t >= 128 && t < 194) {              // 66 f4s of Z
        int s = t - 128;
        long zi = base + 4l * s;
        float4 v = make_float4(0.f, 0.f, 0.f, 0.f);
        if (zi >= 0) v = *(const float4*)(Z + zi);
        zs[4 * s] = v.x; zs[4 * s + 1] = v.y; zs[4 * s + 2] = v.z; zs[4 * s + 3] = v.w;
    } else if (t >= 194 && t < 256) {       // 62 f4s of X (t=194..255)
        int s = t - 194;
        long zi = base + 4l * s;
        float4 v = make_float4(0.f, 0.f, 0.f, 0.f);
        if (zi >= 0) v = *(const float4*)(X + zi);
        xs[4 * s] = v.x; xs[4 * s + 1] = v.y; xs[4 * s + 2] = v.z; xs[4 * s + 3] = v.w;
    } else if (t >= 64 && t < 68) {          // remaining 4 f4s of X (s=62..65)
        int s = t - 64 + 62;
        long zi = base + 4l * s;
        float4 v = make_float4(0.f, 0.f, 0.f, 0.f);
        if (zi >= 0) v = *(const float4*)(X + zi);
        xs[4 * s] = v.x; xs[4 * s + 1] = v.y; xs[4 * s + 2] = v.z; xs[4 * s + 3] = v.w;
    }
    __syncthreads();
    if (t < 8) {                             // entry-gap compose only (no Z replay)
        int i = B * 8 + t;
        int e = 0;
        if (i > 0) {
            int bp = (i - 1) >> 8;           // / SCB (=256)
            unsigned int g = 0;
            for (int k = 0; k < bp; ++k) g = (sBT[k] >> (3 * g)) & 7u;
            e = (int)((L32[i - 1] >> (3 * g)) & 7u);
        }
        eL[t] = (unsigned char)e;
    }
    __syncthreads();
    long q = (long)B * 256 + t;
    int il = t >> 5;                         // sub-chunk within block (0..7)
    int j = t & 31;                          // position within sub-chunk
    int e = (int)eL[il];
    unsigned int mask = smsk[il * 8 + e];
    unsigned int bits = mask & ((j > 0) ? ((1u << j) - 1u) : 0u);
    int a = bits ? (j + __clz(bits) - 32) : (j + e);

    float J0 = 0, J1 = 0, J2 = 0, J3 = 0;
    float H00 = 0, H01 = 0, H03 = 0, H11 = 0, H12 = 0, H13 = 0, H23 = 0, H33 = 0;
    if (a > 0) {
        long m0 = q - a + 1;
        {   // JH_SIMPLE (r13-proven), LDS operands
            int ix = (int)(m0 - 1 - base);
            float x = xs[ix];
            float h = zs[ix];
            H00 = x * d2t1; H11 = h * d2t2;
            J0 = x * dt1; J1 = h * dt2; J2 = x * x; J3 = h * h;
        }
        for (long m = m0 + 1; m <= q; ++m) {   // JH_STEP (r13-proven), LDS operands
            int ix = (int)(m - 1 - base);
            float x = xs[ix];
            float h = zs[ix];
            float av = w2 + w42 * h;
            float g3 = 2.0f * h;
            float g1J0 = dt2 * J0, g1J1 = dt2 * J1, g1J2 = dt2 * J2, g1J3 = dt2 * J3;
            float g3J0 = g3 * J0, g3J1 = g3 * J1, g3J2 = g3 * J2, g3J3 = g3 * J3;
            float n00 = (x * d2t1) + av * H00;
            float n01 = g1J0 + av * H01;
            float n03 = g3J0 + av * H03;
            float n11 = (((h * d2t2) + g1J1) + g1J1) + av * H11;
            float n12 = g1J2 + av * H12;
            float n13 = (g1J3 + g3J1) + av * H13;
            float n23 = g3J2 + av * H23;
            float n33 = (g3J3 + g3J3) + av * H33;
            H00 = n00; H01 = n01; H03 = n03; H11 = n11;
            H12 = n12; H13 = n13; H23 = n23; H33 = n33;
            J0 = (x * dt1) + av * J0;
            J1 = (h * dt2) + av * J1;
            J2 = (x * x) + av * J2;
            J3 = (h * h) + av * J3;
        }
    }
    // J: direct store, dense (lane-consecutive 16 B)
    *((float4*)(Jout + 4 * q)) = make_float4(J0, J1, J2, J3);
    // H: stage into padded LDS (r15-proven exchange)
    float* hr = hx + t * 17;
    hr[0]  = H00; hr[1]  = H01; hr[2]  = 0.0f; hr[3]  = H03;
    hr[4]  = H01; hr[5]  = H11; hr[6]  = H12;  hr[7]  = H13;
    hr[8]  = 0.0f; hr[9] = H12; hr[10] = 0.0f; hr[11] = H23;
    hr[12] = H03; hr[13] = H13; hr[14] = H23;  hr[15] = H33;
    __syncthreads();
    float4* Hp = (float4*)Hout + (long)B * 1024;
#pragma unroll
    for (int rr = 0; rr < 4; ++rr) {
        int f = 256 * rr + t;               // block-local f4 index
        int o = f >> 2;                     // output within block
        int cc = (f & 3) * 4;               // first component of this f4
        const float* s = hx + o * 17 + cc;
        Hp[f] = make_float4(s[0], s[1], s[2], s[3]);
    }
}

extern "C" void kernel_launch(void* const* d_in, const int* in_sizes, int n_in,
                              void* d_out, int out_size, void* d_ws, size_t ws_size,
                              hipStream_t stream) {
    const float* X = (const float*)d_in[0];
    const float* P = (const float*)d_in[1];
    float* out = (float*)d_out;
    float* Z = out;                       // [T]
    float* Jout = out + (long)TLEN;       // [T,4]
    float* Hout = out + 5l * TLEN;        // [T,4,4]

    char* ws = (char*)d_ws;
    float* consts = (float*)ws;                                    // @0, 64 B
    unsigned int* BT = (unsigned int*)(ws + 64);                   // 128 dwords
    unsigned int* tab32 = (unsigned int*)(ws + 1024);              // 128 KB
    unsigned int* L32 = (unsigned int*)(ws + 1024 + (size_t)NSB * 4);      // 128 KB
    unsigned int* Msk = (unsigned int*)(ws + 1024 + 2 * (size_t)NSB * 4);  // 1 MB

    hipLaunchKernelGGL(k_hscan, dim3(TLEN / 8 / 256), dim3(256), 0, stream,
                       P, X, consts, Z);
    hipLaunchKernelGGL(k_tabm, dim3(NSB * 8 / 256), dim3(256), 0, stream,
                       consts, Z, tab32, Msk);
    hipLaunchKernelGGL(k_scanA, dim3(NSCB), dim3(SCB), 0, stream,
                       tab32, L32, BT);
    hipLaunchKernelGGL(k_jh7, dim3(TLEN / 256), dim3(256), 0, stream,
                       X, Z, consts, L32, BT, Msk, Jout, Hout);
}